// Round 1
// baseline (16703.571 us; speedup 1.0000x reference)
//
#include <hip/hip_runtime.h>
#include <hip/hip_cooperative_groups.h>

namespace cg = cooperative_groups;

typedef unsigned short u16;
typedef unsigned int u32;
typedef __bf16 bf16x8 __attribute__((ext_vector_type(8)));
typedef float f32x4 __attribute__((ext_vector_type(4)));
typedef u16 u16x8 __attribute__((ext_vector_type(8)));

#define AS1 __attribute__((address_space(1)))
#define AS3 __attribute__((address_space(3)))

constexpr int Bsz = 512;   // batch
constexpr int LATn = 128;  // latent
constexpr int Hn  = 1024;  // hidden
constexpr int G4H = 4096;  // 4*H
constexpr int BT  = 128;   // batch rows per block
constexpr int JT  = 16;    // hidden units per block
constexpr int GC  = 64;    // gate cols per block (4*JT)
constexpr int NJT = 64;    // Hn/JT
constexpr int NBLK = 256;

__device__ __forceinline__ u16 f2bf(float x){
  u32 u = __float_as_uint(x);
  return (u16)((u + 0x7FFFu + ((u >> 16) & 1u)) >> 16);
}
__device__ __forceinline__ float bf2f(u16 h){ return __uint_as_float(((u32)h) << 16); }

__device__ __forceinline__ float sigm(float x){
  float e = __builtin_amdgcn_exp2f(x * -1.44269504088896f);
  return __builtin_amdgcn_rcpf(1.0f + e);
}
__device__ __forceinline__ float tanh_f(float x){
  float e = __builtin_amdgcn_exp2f(x * -2.88539008177793f);
  return __builtin_amdgcn_rcpf(1.0f + e) * 2.0f - 1.0f;
}

__device__ __forceinline__ bf16x8 ld8(const u16* p){
  u16x8 v = *reinterpret_cast<const u16x8*>(p);
  return __builtin_bit_cast(bf16x8, v);
}

__device__ __forceinline__ void load16_lds(const u16* g, u16* l){
  __builtin_amdgcn_global_load_lds((AS1 void*)(u16*)g, (AS3 void*)l, 16, 0, 0);
}

// ---------------- repack: fp32 -> bf16 hi/lo, gate-interleaved weight layout ----------------
// W_hh src row = g*1024 + j  (g in {i,f,g,o}),  j = jt*16 + r
// dst row' = jt*64 + g*16 + r   (so a block's 64 cols are [g][r] with r = lane&15)
__global__ void repack_kernel(
    const float* __restrict__ Whh, const float* __restrict__ b_ih, const float* __restrict__ b_hh,
    const float* __restrict__ Wih, const float* __restrict__ z,
    const float* __restrict__ Wzh, const float* __restrict__ Wzc,
    u16* wp_hi, u16* wp_lo, u16* zp_hi, u16* zp_lo,
    u16* wzh_hi, u16* wzh_lo, u16* wzc_hi, u16* wzc_lo,
    float* bpack, float* wihpack)
{
  const int idx0 = blockIdx.x * blockDim.x + threadIdx.x;
  const int stride = gridDim.x * blockDim.x;
  for (int i = idx0; i < G4H * Hn; i += stride){
    int row = i >> 10, k = i & 1023;
    int g = row >> 10, jj = row & 1023;
    int drow = (jj >> 4) * GC + g * 16 + (jj & 15);
    float x = Whh[i];
    u16 hi = f2bf(x);
    wp_hi[drow * 1024 + k] = hi;
    wp_lo[drow * 1024 + k] = f2bf(x - bf2f(hi));
  }
  for (int i = idx0; i < Bsz * LATn; i += stride){
    float x = z[i]; u16 hi = f2bf(x);
    zp_hi[i] = hi; zp_lo[i] = f2bf(x - bf2f(hi));
  }
  for (int i = idx0; i < Hn * LATn; i += stride){
    float x = Wzh[i]; u16 h1 = f2bf(x); wzh_hi[i] = h1; wzh_lo[i] = f2bf(x - bf2f(h1));
    float y = Wzc[i]; u16 h2 = f2bf(y); wzc_hi[i] = h2; wzc_lo[i] = f2bf(y - bf2f(h2));
  }
  for (int i = idx0; i < G4H; i += stride){
    int g = i >> 10, jj = i & 1023;
    int drow = (jj >> 4) * GC + g * 16 + (jj & 15);
    bpack[drow] = b_ih[i] + b_hh[i];
    wihpack[drow] = Wih[i];
  }
}

// ---------------- persistent LSTM kernel ----------------
__global__ __launch_bounds__(256, 1) void lstm_persist(
    const u16* __restrict__ wp_hi, const u16* __restrict__ wp_lo,
    const float* __restrict__ bpack, const float* __restrict__ wihpack,
    const float* __restrict__ Wout, const float* __restrict__ bout,
    const u16* __restrict__ zp_hi, const u16* __restrict__ zp_lo,
    const u16* __restrict__ wzh_hi, const u16* __restrict__ wzh_lo,
    const u16* __restrict__ wzc_hi, const u16* __restrict__ wzc_lo,
    const float* __restrict__ bzh, const float* __restrict__ bzc,
    u16* hb_hi, u16* hb_lo,      // [2][512][1024] bf16 hi/lo, double-buffered
    float* ypart,                 // [2][NJT][512]
    float* outp, const int* tlen)
{
  cg::grid_group grid = cg::this_grid();
  __shared__ __align__(16) u16 ldsW[2][2][GC * 64]; // [buf][hi/lo][col*64 + physslot*8], 32 KiB
  __shared__ float x_lds[BT];

  const int tid = threadIdx.x;
  const int lane = tid & 63, w = tid >> 6;
  const int bid = blockIdx.x;
  // XCD-aware mapping: xcd owns 8 j-tiles x all 4 b-tiles -> per-XCD hot set ~= L2
  const int xcd = bid & 7, slot = bid >> 3;
  const int bt = slot & 3;
  const int jt = xcd * 8 + (slot >> 2);

  const int r = lane & 15;   // A-row low / D-col low (j low)
  const int q = lane >> 4;   // k-slot group / D-row quad
  const int j = jt * JT + r;
  const int brow0 = bt * BT + w * 32;

  // per-lane constants
  float bias_r[4], wih_r[4];
  #pragma unroll
  for (int nt = 0; nt < 4; ++nt){
    bias_r[nt] = bpack[jt * GC + nt * 16 + r];
    wih_r[nt]  = wihpack[jt * GC + nt * 16 + r];
  }
  const float wout_r = Wout[j];
  const float bo = bout[0];
  const int T = tlen[0];

  // staging constants (global_load_lds: linear LDS dest, pre-swizzled global src)
  int soff[2], sdst[2];
  #pragma unroll
  for (int i = 0; i < 2; ++i){
    int idx2 = i * 256 + tid;
    int scol = idx2 >> 3, sp = idx2 & 7;
    int s = sp ^ (scol & 7);                    // inverse of read-side swizzle
    soff[i] = (jt * GC + scol) * 1024 + s * 8;  // element offset into packed W
    sdst[i] = (i * 256 + w * 64) * 8;           // wave-uniform LDS base (u16 units)
  }

  auto do_stage = [&](int cc){
    const int buf = cc & 1;
    const int kofs = cc * 64;
    #pragma unroll
    for (int i = 0; i < 2; ++i){
      load16_lds(wp_hi + soff[i] + kofs, &ldsW[buf][0][sdst[i]]);
      load16_lds(wp_lo + soff[i] + kofs, &ldsW[buf][1][sdst[i]]);
    }
  };

  // ---- init: h0 = tanh(z Wzh^T + bzh), c0 = tanh(z Wzc^T + bzc), MFMA over K=128 ----
  f32x4 acc_h[2], acc_c[2];
  {
    float bh0 = bzh[j], bc0 = bzc[j];
    #pragma unroll
    for (int mt = 0; mt < 2; ++mt){
      acc_h[mt] = f32x4{bh0, bh0, bh0, bh0};
      acc_c[mt] = f32x4{bc0, bc0, bc0, bc0};
    }
    #pragma unroll
    for (int ks = 0; ks < 4; ++ks){
      const int ak = ks * 32 + q * 8;
      bf16x8 bhh = ld8(wzh_hi + j * LATn + ak);
      bf16x8 bhl = ld8(wzh_lo + j * LATn + ak);
      bf16x8 bch = ld8(wzc_hi + j * LATn + ak);
      bf16x8 bcl = ld8(wzc_lo + j * LATn + ak);
      #pragma unroll
      for (int mt = 0; mt < 2; ++mt){
        const int arow = brow0 + mt * 16 + r;
        bf16x8 ah = ld8(zp_hi + arow * LATn + ak);
        bf16x8 al = ld8(zp_lo + arow * LATn + ak);
        acc_h[mt] = __builtin_amdgcn_mfma_f32_16x16x32_bf16(ah, bhh, acc_h[mt], 0, 0, 0);
        acc_h[mt] = __builtin_amdgcn_mfma_f32_16x16x32_bf16(ah, bhl, acc_h[mt], 0, 0, 0);
        acc_h[mt] = __builtin_amdgcn_mfma_f32_16x16x32_bf16(al, bhh, acc_h[mt], 0, 0, 0);
        acc_c[mt] = __builtin_amdgcn_mfma_f32_16x16x32_bf16(ah, bch, acc_c[mt], 0, 0, 0);
        acc_c[mt] = __builtin_amdgcn_mfma_f32_16x16x32_bf16(ah, bcl, acc_c[mt], 0, 0, 0);
        acc_c[mt] = __builtin_amdgcn_mfma_f32_16x16x32_bf16(al, bch, acc_c[mt], 0, 0, 0);
      }
    }
  }
  float creg[8];
  #pragma unroll
  for (int mt = 0; mt < 2; ++mt)
    #pragma unroll
    for (int e = 0; e < 4; ++e){
      creg[mt * 4 + e] = tanh_f(acc_c[mt][e]);
      float h0 = tanh_f(acc_h[mt][e]);
      const int b = brow0 + mt * 16 + q * 4 + e;
      u16 hi = f2bf(h0);
      hb_hi[b * Hn + j] = hi;
      hb_lo[b * Hn + j] = f2bf(h0 - bf2f(hi));
    }
  if (tid < BT) x_lds[tid] = 0.0f;
  __syncthreads();
  grid.sync();

  // ---- time loop ----
  #pragma unroll 1
  for (int t = 0; t < T; ++t){
    const int pb = t & 1;
    const u16* __restrict__ hs_hi = hb_hi + pb * (Bsz * Hn);
    const u16* __restrict__ hs_lo = hb_lo + pb * (Bsz * Hn);
    u16* hd_hi = hb_hi + (pb ^ 1) * (Bsz * Hn);
    u16* hd_lo = hb_lo + (pb ^ 1) * (Bsz * Hn);

    float xv[8];
    #pragma unroll
    for (int mt = 0; mt < 2; ++mt)
      #pragma unroll
      for (int e = 0; e < 4; ++e)
        xv[mt * 4 + e] = x_lds[w * 32 + mt * 16 + q * 4 + e];

    f32x4 acc[2][4];
    #pragma unroll
    for (int mt = 0; mt < 2; ++mt)
      #pragma unroll
      for (int nt = 0; nt < 4; ++nt){
        f32x4 a;
        #pragma unroll
        for (int e = 0; e < 4; ++e) a[e] = bias_r[nt] + xv[mt * 4 + e] * wih_r[nt];
        acc[mt][nt] = a;
      }

    do_stage(0);
    for (int c = 0; c < 16; ++c){
      __syncthreads();               // chunk c staged & LDS safe to read
      if (c < 15) do_stage(c + 1);   // overlap next-chunk staging with compute
      #pragma unroll
      for (int sk = 0; sk < 2; ++sk){
        const int ak = c * 64 + sk * 32 + q * 8;
        bf16x8 ahi[2], alo[2];
        #pragma unroll
        for (int mt = 0; mt < 2; ++mt){
          const int arow = brow0 + mt * 16 + r;
          ahi[mt] = ld8(hs_hi + arow * Hn + ak);
          alo[mt] = ld8(hs_lo + arow * Hn + ak);
        }
        const int phys = ((sk * 4 + q) ^ (r & 7)) * 8;
        #pragma unroll
        for (int nt = 0; nt < 4; ++nt){
          const u16* bp = &ldsW[c & 1][0][(nt * 16 + r) * 64 + phys];
          bf16x8 bhi = ld8(bp);
          bf16x8 blo = ld8(bp + GC * 64);
          #pragma unroll
          for (int mt = 0; mt < 2; ++mt){
            acc[mt][nt] = __builtin_amdgcn_mfma_f32_16x16x32_bf16(ahi[mt], bhi, acc[mt][nt], 0, 0, 0);
            acc[mt][nt] = __builtin_amdgcn_mfma_f32_16x16x32_bf16(ahi[mt], blo, acc[mt][nt], 0, 0, 0);
            acc[mt][nt] = __builtin_amdgcn_mfma_f32_16x16x32_bf16(alo[mt], bhi, acc[mt][nt], 0, 0, 0);
          }
        }
      }
    }

    // ---- pointwise LSTM cell (all 4 gates lane-local) ----
    float pp[8];
    #pragma unroll
    for (int mt = 0; mt < 2; ++mt)
      #pragma unroll
      for (int e = 0; e < 4; ++e){
        const int idx = mt * 4 + e;
        float gi = sigm(acc[mt][0][e]);
        float gf = sigm(acc[mt][1][e]);
        float gg = tanh_f(acc[mt][2][e]);
        float go = sigm(acc[mt][3][e]);
        float cn = gf * creg[idx] + gi * gg;
        creg[idx] = cn;
        float hn = go * tanh_f(cn);
        const int b = brow0 + mt * 16 + q * 4 + e;
        u16 hi = f2bf(hn);
        hd_hi[b * Hn + j] = hi;
        hd_lo[b * Hn + j] = f2bf(hn - bf2f(hi));
        pp[idx] = hn * wout_r;
      }
    // reduce over the block's 16 j's (lanes sharing l>>4)
    #pragma unroll
    for (int m = 1; m < 16; m <<= 1)
      #pragma unroll
      for (int idx = 0; idx < 8; ++idx)
        pp[idx] += __shfl_xor(pp[idx], m, 64);
    if (r == 0){
      float* yq = ypart + pb * (NJT * Bsz) + jt * Bsz;
      #pragma unroll
      for (int mt = 0; mt < 2; ++mt)
        #pragma unroll
        for (int e = 0; e < 4; ++e)
          yq[brow0 + mt * 16 + q * 4 + e] = pp[mt * 4 + e];
    }

    grid.sync();

    // ---- x phase: y[b] = b_out + sum over all 64 j-tiles ----
    {
      const int bl = tid >> 1, half = tid & 1;
      const float* yp = ypart + pb * (NJT * Bsz) + bt * BT + bl;
      float s = 0.f;
      #pragma unroll
      for (int j2 = 0; j2 < 32; ++j2) s += yp[(half * 32 + j2) * Bsz];
      s += __shfl_xor(s, 1, 64);
      float y = bo + s;
      if (half == 0){
        x_lds[bl] = y;
        if (jt == 0) outp[(bt * BT + bl) * T + t] = y;
      }
    }
    __syncthreads();
  }
}

extern "C" void kernel_launch(void* const* d_in, const int* in_sizes, int n_in,
                              void* d_out, int out_size, void* d_ws, size_t ws_size,
                              hipStream_t stream)
{
  const float* z    = (const float*)d_in[0];
  const float* Wzh  = (const float*)d_in[1];
  const float* bzh  = (const float*)d_in[2];
  const float* Wzc  = (const float*)d_in[3];
  const float* bzc  = (const float*)d_in[4];
  const float* Wih  = (const float*)d_in[5];
  const float* Whh  = (const float*)d_in[6];
  const float* b_ih = (const float*)d_in[7];
  const float* b_hh = (const float*)d_in[8];
  const float* Wout = (const float*)d_in[9];
  const float* bout = (const float*)d_in[10];
  const int*   tlen = (const int*)d_in[11];
  float* outp = (float*)d_out;

  char* ws = (char*)d_ws;
  size_t off = 0;
  auto alloc = [&](size_t bytes) -> char* {
    char* p = ws + off;
    off += (bytes + 255) & ~size_t(255);
    return p;
  };
  u16* wp_hi  = (u16*)alloc((size_t)G4H * Hn * 2);
  u16* wp_lo  = (u16*)alloc((size_t)G4H * Hn * 2);
  u16* hb_hi  = (u16*)alloc((size_t)2 * Bsz * Hn * 2);
  u16* hb_lo  = (u16*)alloc((size_t)2 * Bsz * Hn * 2);
  u16* zp_hi  = (u16*)alloc((size_t)Bsz * LATn * 2);
  u16* zp_lo  = (u16*)alloc((size_t)Bsz * LATn * 2);
  u16* wzh_hi = (u16*)alloc((size_t)Hn * LATn * 2);
  u16* wzh_lo = (u16*)alloc((size_t)Hn * LATn * 2);
  u16* wzc_hi = (u16*)alloc((size_t)Hn * LATn * 2);
  u16* wzc_lo = (u16*)alloc((size_t)Hn * LATn * 2);
  float* bpack   = (float*)alloc((size_t)G4H * 4);
  float* wihpack = (float*)alloc((size_t)G4H * 4);
  float* ypart   = (float*)alloc((size_t)2 * NJT * Bsz * 4);

  repack_kernel<<<dim3(1024), dim3(256), 0, stream>>>(
      Whh, b_ih, b_hh, Wih, z, Wzh, Wzc,
      wp_hi, wp_lo, zp_hi, zp_lo, wzh_hi, wzh_lo, wzc_hi, wzc_lo,
      bpack, wihpack);

  void* args[] = {
    (void*)&wp_hi, (void*)&wp_lo, (void*)&bpack, (void*)&wihpack,
    (void*)&Wout, (void*)&bout,
    (void*)&zp_hi, (void*)&zp_lo,
    (void*)&wzh_hi, (void*)&wzh_lo, (void*)&wzc_hi, (void*)&wzc_lo,
    (void*)&bzh, (void*)&bzc,
    (void*)&hb_hi, (void*)&hb_lo,
    (void*)&ypart, (void*)&outp, (void*)&tlen
  };
  hipLaunchCooperativeKernel(reinterpret_cast<void*>(lstm_persist),
                             dim3(NBLK), dim3(256), args, 0, stream);
}

// Round 3
// 15309.572 us; speedup vs baseline: 1.0911x; 1.0911x over previous
//
#include <hip/hip_runtime.h>

typedef unsigned short u16;
typedef unsigned int u32;
typedef __bf16 bf16x8 __attribute__((ext_vector_type(8)));
typedef float f32x4 __attribute__((ext_vector_type(4)));
typedef u16 u16x8 __attribute__((ext_vector_type(8)));

#define AS1 __attribute__((address_space(1)))
#define AS3 __attribute__((address_space(3)))

constexpr int Bsz = 512;   // batch
constexpr int LATn = 128;  // latent
constexpr int Hn  = 1024;  // hidden
constexpr int G4H = 4096;  // 4*H
constexpr int NBLK = 256;

__device__ __forceinline__ u16 f2bf(float x){
  u32 u = __float_as_uint(x);
  return (u16)((u + 0x7FFFu + ((u >> 16) & 1u)) >> 16);
}
__device__ __forceinline__ float bf2f(u16 h){ return __uint_as_float(((u32)h) << 16); }

__device__ __forceinline__ float sigm(float x){
  float e = __builtin_amdgcn_exp2f(x * -1.44269504088896f);
  return __builtin_amdgcn_rcpf(1.0f + e);
}
__device__ __forceinline__ float tanh_f(float x){
  float e = __builtin_amdgcn_exp2f(x * -2.88539008177793f);
  return __builtin_amdgcn_rcpf(1.0f + e) * 2.0f - 1.0f;
}

__device__ __forceinline__ bf16x8 ld8(const u16* p){
  u16x8 v = *reinterpret_cast<const u16x8*>(p);
  return __builtin_bit_cast(bf16x8, v);
}

__device__ __forceinline__ void load16_lds(const u16* g, u16* l){
  __builtin_amdgcn_global_load_lds((AS1 void*)(u16*)g, (AS3 void*)l, 16, 0, 0);
}

// ---------------- repack: fp32 -> bf16 hi/lo, gate-interleaved weight layout ----------------
// W_hh src row = g*1024 + jj  (gate-major packed col: drow = (jj>>4)*64 + g*16 + (jj&15))
__global__ void repack_kernel(
    const float* __restrict__ Whh, const float* __restrict__ b_ih, const float* __restrict__ b_hh,
    const float* __restrict__ Wih, const float* __restrict__ z,
    const float* __restrict__ Wzh, const float* __restrict__ Wzc,
    u16* wp_hi, u16* wp_lo, u16* zp_hi, u16* zp_lo,
    u16* wzh_hi, u16* wzh_lo, u16* wzc_hi, u16* wzc_lo,
    float* bpack, float* wihpack, u32* cnt)
{
  const int idx0 = blockIdx.x * blockDim.x + threadIdx.x;
  const int stride = gridDim.x * blockDim.x;
  if (idx0 < 4) cnt[idx0] = 0u;   // group-barrier counters: zero every launch
  for (int i = idx0; i < G4H * Hn; i += stride){
    int row = i >> 10, k = i & 1023;
    int g = row >> 10, jj = row & 1023;
    int drow = (jj >> 4) * 64 + g * 16 + (jj & 15);
    float x = Whh[i];
    u16 hi = f2bf(x);
    wp_hi[drow * 1024 + k] = hi;
    wp_lo[drow * 1024 + k] = f2bf(x - bf2f(hi));
  }
  for (int i = idx0; i < Bsz * LATn; i += stride){
    float x = z[i]; u16 hi = f2bf(x);
    zp_hi[i] = hi; zp_lo[i] = f2bf(x - bf2f(hi));
  }
  for (int i = idx0; i < Hn * LATn; i += stride){
    float x = Wzh[i]; u16 h1 = f2bf(x); wzh_hi[i] = h1; wzh_lo[i] = f2bf(x - bf2f(h1));
    float y = Wzc[i]; u16 h2 = f2bf(y); wzc_hi[i] = h2; wzc_lo[i] = f2bf(y - bf2f(h2));
  }
  for (int i = idx0; i < G4H; i += stride){
    int g = i >> 10, jj = i & 1023;
    int drow = (jj >> 4) * 64 + g * 16 + (jj & 15);
    bpack[drow] = b_ih[i] + b_hh[i];
    wihpack[drow] = Wih[i];
  }
}

// ---------------- persistent LSTM kernel ----------------
// 256 blocks x 256 threads, PLAIN launch (1 block/CU by LDS; grid == CU count).
// Block (bt,jt): bt = (bid&7)>>1, jt = (bid>>3)*2+(bid&1)  -> each XCD holds one bt group half.
// 4 waves = 2 batch-groups (64 rows) x 2 k-halves (512). Whi LDS-resident; Wlo from global;
// h exchanged via hand-rolled 64-block group barrier (agent fences + relaxed atomic counter).
__global__ __launch_bounds__(256, 1) void lstm_persist(
    const u16* __restrict__ wp_hi, const u16* __restrict__ wp_lo,
    const float* __restrict__ bpack, const float* __restrict__ wihpack,
    const float* __restrict__ Wout, const float* __restrict__ bout,
    const u16* __restrict__ zp_hi, const u16* __restrict__ zp_lo,
    const u16* __restrict__ wzh_hi, const u16* __restrict__ wzh_lo,
    const u16* __restrict__ wzc_hi, const u16* __restrict__ wzc_lo,
    const float* __restrict__ bzh, const float* __restrict__ bzc,
    u16* hb_hi, u16* hb_lo,      // [2][512][1024] bf16 hi/lo, double-buffered
    float* ypart,                 // [2][64][512]
    float* outp, const int* tlen, u32* cnt)
{
  __shared__ __align__(16) u16 ldsW[16 * 4096];  // 128 KiB: [c64][col][slot^swz][8]
  __shared__ float exch[4096];                   // 16 KiB k-partial exchange
  __shared__ float x_lds[128];

  const int tid = threadIdx.x;
  const int lane = tid & 63, w = tid >> 6;
  const int r = lane & 15, q = lane >> 4;
  const int bgroup = w & 1, kg = w >> 1;
  const int bid = blockIdx.x;
  const int bt = (bid & 7) >> 1;
  const int jt = ((bid >> 3) << 1) | (bid & 1);
  const int j = jt * 16 + r;
  const int T = tlen[0];

  // ---- stage Whi into LDS (once) ----
  #pragma unroll 4
  for (int c64 = 0; c64 < 16; ++c64){
    #pragma unroll
    for (int i = 0; i < 2; ++i){
      int idx = i * 256 + tid;
      int scol = idx >> 3, sp = idx & 7;
      int s = sp ^ (scol & 7);                        // inverse of read-side swizzle
      load16_lds(wp_hi + (size_t)(jt * 64 + scol) * 1024 + c64 * 64 + s * 8,
                 &ldsW[c64 * 4096 + i * 2048 + w * 512]);   // wave-uniform dst + lane*16B
    }
  }

  // per-lane constants
  float bias_r[4], wih_r[4];
  #pragma unroll
  for (int nt = 0; nt < 4; ++nt){
    bias_r[nt] = bpack[jt * 64 + nt * 16 + r];
    wih_r[nt]  = wihpack[jt * 64 + nt * 16 + r];
  }
  const float wout_r = Wout[j];
  const float bo = bout[0];

  // ---- init: h0 = tanh(z Wzh^T + bzh), c0 = tanh(z Wzc^T + bzc) (kg==0 waves) ----
  float creg[16];
  if (kg == 0){
    const float bh0 = bzh[j], bc0 = bzc[j];
    f32x4 acc_h[4], acc_c[4];
    #pragma unroll
    for (int mt = 0; mt < 4; ++mt){
      acc_h[mt] = f32x4{bh0, bh0, bh0, bh0};
      acc_c[mt] = f32x4{bc0, bc0, bc0, bc0};
    }
    #pragma unroll
    for (int ks = 0; ks < 4; ++ks){
      const int ak = ks * 32 + q * 8;
      bf16x8 bhh = ld8(wzh_hi + j * LATn + ak);
      bf16x8 bhl = ld8(wzh_lo + j * LATn + ak);
      bf16x8 bch = ld8(wzc_hi + j * LATn + ak);
      bf16x8 bcl = ld8(wzc_lo + j * LATn + ak);
      #pragma unroll
      for (int mt = 0; mt < 4; ++mt){
        const int arow = bt * 128 + bgroup * 64 + mt * 16 + r;
        bf16x8 ah = ld8(zp_hi + arow * LATn + ak);
        bf16x8 al = ld8(zp_lo + arow * LATn + ak);
        acc_h[mt] = __builtin_amdgcn_mfma_f32_16x16x32_bf16(ah, bhh, acc_h[mt], 0, 0, 0);
        acc_h[mt] = __builtin_amdgcn_mfma_f32_16x16x32_bf16(ah, bhl, acc_h[mt], 0, 0, 0);
        acc_h[mt] = __builtin_amdgcn_mfma_f32_16x16x32_bf16(al, bhh, acc_h[mt], 0, 0, 0);
        acc_c[mt] = __builtin_amdgcn_mfma_f32_16x16x32_bf16(ah, bch, acc_c[mt], 0, 0, 0);
        acc_c[mt] = __builtin_amdgcn_mfma_f32_16x16x32_bf16(ah, bcl, acc_c[mt], 0, 0, 0);
        acc_c[mt] = __builtin_amdgcn_mfma_f32_16x16x32_bf16(al, bch, acc_c[mt], 0, 0, 0);
      }
    }
    #pragma unroll
    for (int mt = 0; mt < 4; ++mt)
      #pragma unroll
      for (int e = 0; e < 4; ++e){
        const int idx = mt * 4 + e;
        creg[idx] = tanh_f(acc_c[mt][e]);
        float h0 = tanh_f(acc_h[mt][e]);
        const int row = bt * 128 + bgroup * 64 + mt * 16 + q * 4 + e;
        u16 hi = f2bf(h0);
        hb_hi[row * Hn + j] = hi;
        hb_lo[row * Hn + j] = f2bf(h0 - bf2f(hi));
      }
  }
  if (tid < 128) x_lds[tid] = 0.0f;
  __syncthreads();

  // ---- group barrier (64 blocks sharing bt), hand-rolled; capped spin as hang hedge ----
  __builtin_amdgcn_fence(__ATOMIC_RELEASE, "agent");
  __syncthreads();
  if (tid == 0){
    __hip_atomic_fetch_add(cnt + bt, 1u, __ATOMIC_RELAXED, __HIP_MEMORY_SCOPE_AGENT);
    for (int spin = 0; spin < (1 << 18); ++spin){
      if (__hip_atomic_load(cnt + bt, __ATOMIC_RELAXED, __HIP_MEMORY_SCOPE_AGENT) >= 64u) break;
      __builtin_amdgcn_s_sleep(2);
    }
  }
  __syncthreads();
  __builtin_amdgcn_fence(__ATOMIC_ACQUIRE, "agent");

  // ---- time loop ----
  #pragma unroll 1
  for (int t = 0; t < T; ++t){
    const int pb = t & 1;
    const u16* hs_hi = hb_hi + pb * (Bsz * Hn);
    const u16* hs_lo = hb_lo + pb * (Bsz * Hn);
    u16* hd_hi = hb_hi + (pb ^ 1) * (Bsz * Hn);
    u16* hd_lo = hb_lo + (pb ^ 1) * (Bsz * Hn);

    f32x4 acc[4][4];
    if (kg == 0){
      #pragma unroll
      for (int mt = 0; mt < 4; ++mt)
        #pragma unroll
        for (int e = 0; e < 4; ++e){
          const float xv = x_lds[bgroup * 64 + mt * 16 + q * 4 + e];
          #pragma unroll
          for (int nt = 0; nt < 4; ++nt)
            acc[mt][nt][e] = bias_r[nt] + xv * wih_r[nt];
        }
    } else {
      #pragma unroll
      for (int mt = 0; mt < 4; ++mt)
        #pragma unroll
        for (int nt = 0; nt < 4; ++nt)
          acc[mt][nt] = f32x4{0.f, 0.f, 0.f, 0.f};
    }

    const u16* ha_hi = hs_hi + (bt * 128 + bgroup * 64 + r) * Hn + kg * 512 + q * 8;
    const u16* ha_lo = hs_lo + (bt * 128 + bgroup * 64 + r) * Hn + kg * 512 + q * 8;
    const u16* wl    = wp_lo + (size_t)(jt * 64 + r) * 1024 + kg * 512 + q * 8;

    #pragma unroll 4
    for (int c32 = 0; c32 < 16; ++c32){
      const int ko = c32 * 32;
      bf16x8 ahi[4], alo[4], bhi[4], blo[4];
      #pragma unroll
      for (int mt = 0; mt < 4; ++mt){
        ahi[mt] = ld8(ha_hi + mt * 16 * Hn + ko);
        alo[mt] = ld8(ha_lo + mt * 16 * Hn + ko);
      }
      const int c64o = (kg * 8 + (c32 >> 1)) * 4096;
      const int slot = ((((c32 & 1) * 4 + q) ^ (r & 7))) * 8;
      #pragma unroll
      for (int nt = 0; nt < 4; ++nt){
        bhi[nt] = ld8(&ldsW[c64o + (nt * 16 + r) * 64 + slot]);
        blo[nt] = ld8(wl + nt * 16 * 1024 + ko);
      }
      #pragma unroll
      for (int mt = 0; mt < 4; ++mt)
        #pragma unroll
        for (int nt = 0; nt < 4; ++nt){
          acc[mt][nt] = __builtin_amdgcn_mfma_f32_16x16x32_bf16(ahi[mt], bhi[nt], acc[mt][nt], 0, 0, 0);
          acc[mt][nt] = __builtin_amdgcn_mfma_f32_16x16x32_bf16(ahi[mt], blo[nt], acc[mt][nt], 0, 0, 0);
          acc[mt][nt] = __builtin_amdgcn_mfma_f32_16x16x32_bf16(alo[mt], bhi[nt], acc[mt][nt], 0, 0, 0);
        }
    }

    // ---- k-half partial-sum exchange through LDS (w0<-w2, w1<-w3) ----
    __syncthreads();
    if (w == 2){
      #pragma unroll
      for (int mt = 0; mt < 4; ++mt)
        #pragma unroll
        for (int nt = 0; nt < 4; ++nt)
          #pragma unroll
          for (int e = 0; e < 4; ++e)
            exch[(mt * 4 + nt) * 256 + e * 64 + lane] = acc[mt][nt][e];
    }
    __syncthreads();
    if (w == 0){
      #pragma unroll
      for (int mt = 0; mt < 4; ++mt)
        #pragma unroll
        for (int nt = 0; nt < 4; ++nt)
          #pragma unroll
          for (int e = 0; e < 4; ++e)
            acc[mt][nt][e] += exch[(mt * 4 + nt) * 256 + e * 64 + lane];
    }
    __syncthreads();
    if (w == 3){
      #pragma unroll
      for (int mt = 0; mt < 4; ++mt)
        #pragma unroll
        for (int nt = 0; nt < 4; ++nt)
          #pragma unroll
          for (int e = 0; e < 4; ++e)
            exch[(mt * 4 + nt) * 256 + e * 64 + lane] = acc[mt][nt][e];
    }
    __syncthreads();
    if (w == 1){
      #pragma unroll
      for (int mt = 0; mt < 4; ++mt)
        #pragma unroll
        for (int nt = 0; nt < 4; ++nt)
          #pragma unroll
          for (int e = 0; e < 4; ++e)
            acc[mt][nt][e] += exch[(mt * 4 + nt) * 256 + e * 64 + lane];
    }

    // ---- pointwise LSTM cell (kg0 waves; all 4 gates lane-local) ----
    if (kg == 0){
      float pp[16];
      #pragma unroll
      for (int mt = 0; mt < 4; ++mt)
        #pragma unroll
        for (int e = 0; e < 4; ++e){
          const int idx = mt * 4 + e;
          float gi = sigm(acc[mt][0][e]);
          float gf = sigm(acc[mt][1][e]);
          float gg = tanh_f(acc[mt][2][e]);
          float go = sigm(acc[mt][3][e]);
          float cn = gf * creg[idx] + gi * gg;
          creg[idx] = cn;
          float hn = go * tanh_f(cn);
          const int row = bt * 128 + bgroup * 64 + mt * 16 + q * 4 + e;
          u16 hi = f2bf(hn);
          hd_hi[row * Hn + j] = hi;
          hd_lo[row * Hn + j] = f2bf(hn - bf2f(hi));
          pp[idx] = hn * wout_r;
        }
      #pragma unroll
      for (int m = 1; m < 16; m <<= 1)
        #pragma unroll
        for (int idx = 0; idx < 16; ++idx)
          pp[idx] += __shfl_xor(pp[idx], m, 64);
      if (r == 0){
        #pragma unroll
        for (int mt = 0; mt < 4; ++mt)
          #pragma unroll
          for (int e = 0; e < 4; ++e)
            ypart[pb * 32768 + jt * 512 + bt * 128 + bgroup * 64 + mt * 16 + q * 4 + e] = pp[mt * 4 + e];
      }
    }

    // ---- group barrier ----
    __builtin_amdgcn_fence(__ATOMIC_RELEASE, "agent");
    __syncthreads();
    if (tid == 0){
      __hip_atomic_fetch_add(cnt + bt, 1u, __ATOMIC_RELAXED, __HIP_MEMORY_SCOPE_AGENT);
      const u32 tgt = 64u * (u32)(t + 2);
      for (int spin = 0; spin < (1 << 18); ++spin){
        if (__hip_atomic_load(cnt + bt, __ATOMIC_RELAXED, __HIP_MEMORY_SCOPE_AGENT) >= tgt) break;
        __builtin_amdgcn_s_sleep(2);
      }
    }
    __syncthreads();
    __builtin_amdgcn_fence(__ATOMIC_ACQUIRE, "agent");

    // ---- x phase: y[b] = b_out + sum over all 64 j-tiles ----
    {
      const int row = tid >> 1, half = tid & 1;
      const float* yp = ypart + pb * 32768 + bt * 128 + row;
      float s = 0.f;
      #pragma unroll
      for (int j2 = 0; j2 < 32; ++j2) s += yp[(half * 32 + j2) * 512];
      s += __shfl_xor(s, 1, 64);
      if (half == 0){
        const float y = bo + s;
        x_lds[row] = y;
        if (jt == 0) outp[(bt * 128 + row) * T + t] = y;
      }
    }
    __syncthreads();
  }
}

extern "C" void kernel_launch(void* const* d_in, const int* in_sizes, int n_in,
                              void* d_out, int out_size, void* d_ws, size_t ws_size,
                              hipStream_t stream)
{
  const float* z    = (const float*)d_in[0];
  const float* Wzh  = (const float*)d_in[1];
  const float* bzh  = (const float*)d_in[2];
  const float* Wzc  = (const float*)d_in[3];
  const float* bzc  = (const float*)d_in[4];
  const float* Wih  = (const float*)d_in[5];
  const float* Whh  = (const float*)d_in[6];
  const float* b_ih = (const float*)d_in[7];
  const float* b_hh = (const float*)d_in[8];
  const float* Wout = (const float*)d_in[9];
  const float* bout = (const float*)d_in[10];
  const int*   tlen = (const int*)d_in[11];
  float* outp = (float*)d_out;

  char* ws = (char*)d_ws;
  size_t off = 0;
  auto alloc = [&](size_t bytes) -> char* {
    char* p = ws + off;
    off += (bytes + 255) & ~size_t(255);
    return p;
  };
  u16* wp_hi  = (u16*)alloc((size_t)G4H * Hn * 2);
  u16* wp_lo  = (u16*)alloc((size_t)G4H * Hn * 2);
  u16* hb_hi  = (u16*)alloc((size_t)2 * Bsz * Hn * 2);
  u16* hb_lo  = (u16*)alloc((size_t)2 * Bsz * Hn * 2);
  u16* zp_hi  = (u16*)alloc((size_t)Bsz * LATn * 2);
  u16* zp_lo  = (u16*)alloc((size_t)Bsz * LATn * 2);
  u16* wzh_hi = (u16*)alloc((size_t)Hn * LATn * 2);
  u16* wzh_lo = (u16*)alloc((size_t)Hn * LATn * 2);
  u16* wzc_hi = (u16*)alloc((size_t)Hn * LATn * 2);
  u16* wzc_lo = (u16*)alloc((size_t)Hn * LATn * 2);
  float* bpack   = (float*)alloc((size_t)G4H * 4);
  float* wihpack = (float*)alloc((size_t)G4H * 4);
  float* ypart   = (float*)alloc((size_t)2 * 64 * Bsz * 4);
  u32* cnt       = (u32*)alloc(256);

  repack_kernel<<<dim3(1024), dim3(256), 0, stream>>>(
      Whh, b_ih, b_hh, Wih, z, Wzh, Wzc,
      wp_hi, wp_lo, zp_hi, zp_lo, wzh_hi, wzh_lo, wzc_hi, wzc_lo,
      bpack, wihpack, cnt);

  lstm_persist<<<dim3(NBLK), dim3(256), 0, stream>>>(
      wp_hi, wp_lo, bpack, wihpack, Wout, bout,
      zp_hi, zp_lo, wzh_hi, wzh_lo, wzc_hi, wzc_lo,
      bzh, bzc, hb_hi, hb_lo, ypart, outp, tlen, cnt);
}